// Round 10
// baseline (1253.450 us; speedup 1.0000x reference)
//
#include <hip/hip_runtime.h>
#include <hip/hip_bf16.h>
#include <math.h>

#define T_TOK 8192
#define DMODEL 512
#define NHEAD 8
#define TEDIM 192
#define DFF 1365
#define DFFP 1408
#define KP2 1376
#define NLAYER 3
#define WINSZ 128
#define NBLK 16
#define LSEQ 2048
#define BATCH 4

typedef unsigned short ushort_t;
typedef __bf16 bf16x8 __attribute__((ext_vector_type(8)));
typedef float f32x4 __attribute__((ext_vector_type(4)));
typedef float f32x16 __attribute__((ext_vector_type(16)));

__device__ __forceinline__ float silu_f(float x) { return x / (1.0f + expf(-x)); }
__device__ __forceinline__ float softplus_f(float x) {
    return (x > 20.0f) ? x : log1pf(expf(x));
}

__device__ __forceinline__ ushort_t f2u(float x) {
    __hip_bfloat16 b = __float2bfloat16(x);
    return *reinterpret_cast<ushort_t*>(&b);
}
__device__ __forceinline__ float u2f(ushort_t u) {
    __hip_bfloat16 b = *reinterpret_cast<__hip_bfloat16*>(&u);
    return __bfloat162float(b);
}
__device__ __forceinline__ void split2(float x, ushort_t& hi, ushort_t& lo) {
    hi = f2u(x);
    lo = f2u(x - u2f(hi));
}

__device__ __forceinline__ void gl_lds16(const ushort_t* g, ushort_t* l) {
    __builtin_amdgcn_global_load_lds(
        (const __attribute__((address_space(1))) unsigned int*)g,
        (__attribute__((address_space(3))) unsigned int*)l, 16, 0, 0);
}

// ---------------- RoPE table + encoder combined weight (merged) ---------------
__global__ __launch_bounds__(256)
void prep_const(float* __restrict__ ct, float* __restrict__ st,
                const float* __restrict__ reg_w, const float* __restrict__ reg_b,
                const float* __restrict__ br_w, const float* __restrict__ br_b,
                const float* __restrict__ sh_w, const float* __restrict__ sh_b,
                ushort_t* __restrict__ Wc2, float* __restrict__ bc) {
    int bx = blockIdx.x;
    int tid = threadIdx.x;
    if (bx < 256) {
        int idx = bx * 256 + tid;
        int tok = idx >> 5, p = idx & 31;
        float invf = powf(10000.0f, -(float)p * (1.0f / 32.0f));
        float sn, cs;
        sincosf((float)tok * invf, &sn, &cs);
        ct[idx] = cs;
        st[idx] = sn;
        return;
    }
    int n = bx - 256;
    for (int k = tid; k < 288; k += 256) {
        float v = 0.0f;
        if (n < 192) {
            if (k < 64) v = reg_w[(size_t)n * 64 + k];
        } else if (n < 384) {
            if (k >= 256) v = br_w[(size_t)(n - 192) * 32 + (k - 256)];
        } else if (n < 576) {
            if (k >= 64 && k < 256) v = sh_w[(size_t)(n - 384) * 192 + (k - 64)];
        }
        ushort_t hi, lo;
        split2(v, hi, lo);
        Wc2[(size_t)n * 576 + k] = hi;
        Wc2[(size_t)n * 576 + 288 + k] = lo;
    }
    if (tid == 0) {
        float b = 0.0f;
        if (n < 192) b = reg_b[n];
        else if (n < 384) b = br_b[n - 192];
        else if (n < 576) b = sh_b[n - 384];
        bc[n] = b;
    }
}

// ---------------- weight splits ------------------------------------------------
__global__ __launch_bounds__(256)
void splitw_kernel(const float* __restrict__ W, ushort_t* __restrict__ W2,
                   int N, int K, int Kp) {
    int n = blockIdx.y;
    int k = blockIdx.x * 256 + threadIdx.x;
    if (k >= Kp) return;
    float v = (n < N && k < K) ? W[(size_t)n * K + k] : 0.0f;
    ushort_t hi, lo;
    split2(v, hi, lo);
    W2[(size_t)n * (2 * Kp) + k] = hi;
    W2[(size_t)n * (2 * Kp) + Kp + k] = lo;
}

__global__ __launch_bounds__(256)
void splitw_qkv_kernel(const float* __restrict__ W, ushort_t* __restrict__ W2) {
    int l = blockIdx.z;
    int rr = blockIdx.y;
    int k = blockIdx.x * 256 + threadIdx.x;
    int h = rr / 192, rem = rr % 192;
    int dk = rem / 3, which = rem % 3;
    int rp = which * 512 + h * 64 + dk;
    float v = W[((size_t)l * 1536 + rr) * 512 + k];
    ushort_t hi, lo;
    split2(v, hi, lo);
    W2[((size_t)l * 1536 + rp) * 1024 + k] = hi;
    W2[((size_t)l * 1536 + rp) * 1024 + 512 + k] = lo;
}

__global__ __launch_bounds__(256)
void splitw_ffn(const float* __restrict__ w1, const float* __restrict__ w3,
                ushort_t* __restrict__ W1s, ushort_t* __restrict__ W3s) {
    int rr = blockIdx.y;
    int k = blockIdx.x * 256 + threadIdx.x;
    int lyr = rr / DFFP, n = rr % DFFP;
    bool ok = (n < DFF);
    float v1 = ok ? w1[((size_t)lyr * DFF + n) * 512 + k] : 0.0f;
    float v3 = ok ? w3[((size_t)lyr * DFF + n) * 512 + k] : 0.0f;
    ushort_t hi, lo;
    split2(v1, hi, lo);
    W1s[(size_t)rr * 1024 + k] = hi;
    W1s[(size_t)rr * 1024 + 512 + k] = lo;
    split2(v3, hi, lo);
    W3s[(size_t)rr * 1024 + k] = hi;
    W3s[(size_t)rr * 1024 + 512 + k] = lo;
}

__global__ __launch_bounds__(256)
void splitw_w2(const float* __restrict__ W, ushort_t* __restrict__ W2) {
    int rr = blockIdx.y;
    int k = blockIdx.x * 256 + threadIdx.x;
    if (k >= KP2) return;
    int lyr = rr >> 9, n = rr & 511;
    float v = (k < DFF) ? W[((size_t)lyr * 512 + n) * DFF + k] : 0.0f;
    ushort_t hi, lo;
    split2(v, hi, lo);
    W2[(size_t)rr * (2 * KP2) + k] = hi;
    W2[(size_t)rr * (2 * KP2) + KP2 + k] = lo;
}

// ---------------- token prep (X hi only — ints are bf16-exact) ----------------
__global__ __launch_bounds__(256)
void prep_tok(const int* __restrict__ x, const float* __restrict__ emb,
              ushort_t* __restrict__ X2, ushort_t* __restrict__ cat2) {
    int tok = blockIdx.x;
    int tid = threadIdx.x;
    const int* xp = x + (size_t)tok * 289;
    for (int k = tid; k < 288; k += 256)
        X2[(size_t)tok * 288 + k] = f2u((float)xp[1 + k]);
    int tokid = xp[0];
    for (int c = tid; c < 192; c += 256) {
        float v = silu_f(emb[(size_t)tokid * TEDIM + c]);
        ushort_t hi, lo;
        split2(v, hi, lo);
        cat2[(size_t)tok * 1536 + c] = hi;
        cat2[(size_t)tok * 1536 + 768 + c] = lo;
    }
}

// ======== GEMM machinery ======================================================
// LDS: [rows][4 x 16B k-chunks]. Chunk c of row r at slot (c + (r>>1)) & 3.
// Staging lane tid: global chunk ((tid&3) - (tid>>3)) & 3 of row tid>>2.
// XCD swizzle: N-tile index is blockIdx.x with gridDim.x % 8 == 0 (pad +
// early-exit), so XCD = linear_id % 8 = bn_tile % 8 -> each XCD's weight
// tiles stay L2-resident across all M blocks.

#define MFMA32(a, b, c) __builtin_amdgcn_mfma_f32_32x32x16_bf16(a, b, c, 0, 0, 0)
#define MFMA16(a, b, c) __builtin_amdgcn_mfma_f32_16x16x32_bf16(a, b, c, 0, 0, 0)

// ---------------- 128x128 GEMM, 16x16 frags; grid (Npad16, 64) ----------------
__global__ __launch_bounds__(256)
void gemm3_kernel(const ushort_t* __restrict__ A2, int rsA,
                  const ushort_t* __restrict__ B2, int rsB,
                  const float* __restrict__ bias,
                  const float* __restrict__ res,
                  float* __restrict__ Cf, int rsC, int Kp, int Nlim) {
    const int bn = blockIdx.x * 128;
    if (bn >= Nlim) return;
    const int bm = blockIdx.y * 128;
    __shared__ __align__(16) ushort_t lds[4 * 4096];
    const int tid = threadIdx.x;
    const int w = tid >> 6, l = tid & 63;
    const int wm = (w & 1) * 64, wn = (w >> 1) * 64;

    f32x4 acc[4][4];
    #pragma unroll
    for (int i = 0; i < 4; ++i)
        #pragma unroll
        for (int j = 0; j < 4; ++j) acc[i][j] = (f32x4){0.f, 0.f, 0.f, 0.f};

    const int r0 = tid >> 2;
    const int k8 = (((tid & 3) - (tid >> 3)) & 3) * 8;
    const ushort_t* gA0 = A2 + (size_t)(bm + r0) * rsA + k8;
    const ushort_t* gA1 = A2 + (size_t)(bm + 64 + r0) * rsA + k8;
    const ushort_t* gB0 = B2 + (size_t)(bn + r0) * rsB + k8;
    const ushort_t* gB1 = B2 + (size_t)(bn + 64 + r0) * rsB + k8;
    ushort_t* l0 = lds + tid * 8;
    ushort_t* l1 = lds + 2048 + tid * 8;

    const int fr = l & 15, q = l >> 4;

    for (int kt = 0; kt < Kp; kt += 32) {
        gl_lds16(gA0 + kt, l0);
        gl_lds16(gA1 + kt, l1);
        gl_lds16(gA0 + kt + Kp, l0 + 4096);
        gl_lds16(gA1 + kt + Kp, l1 + 4096);
        gl_lds16(gB0 + kt, l0 + 8192);
        gl_lds16(gB1 + kt, l1 + 8192);
        gl_lds16(gB0 + kt + Kp, l0 + 12288);
        gl_lds16(gB1 + kt + Kp, l1 + 12288);
        __syncthreads();

        bf16x8 ahi[4], alo[4], bhi[4], blo[4];
        #pragma unroll
        for (int i = 0; i < 4; ++i) {
            int rowa = wm + i * 16 + fr;
            int ba = rowa * 32 + (((q + (rowa >> 1)) & 3) * 8);
            ahi[i] = *(const bf16x8*)&lds[ba];
            alo[i] = *(const bf16x8*)&lds[4096 + ba];
            int rowb = wn + i * 16 + fr;
            int bb = rowb * 32 + (((q + (rowb >> 1)) & 3) * 8);
            bhi[i] = *(const bf16x8*)&lds[8192 + bb];
            blo[i] = *(const bf16x8*)&lds[12288 + bb];
        }
        #pragma unroll
        for (int i = 0; i < 4; ++i)
            #pragma unroll
            for (int j = 0; j < 4; ++j) {
                acc[i][j] = MFMA16(ahi[i], bhi[j], acc[i][j]);
                acc[i][j] = MFMA16(ahi[i], blo[j], acc[i][j]);
                acc[i][j] = MFMA16(alo[i], bhi[j], acc[i][j]);
            }
        __syncthreads();
    }

    const int er = (l >> 4) * 4, ec = l & 15;
    #pragma unroll
    for (int i = 0; i < 4; ++i)
        #pragma unroll
        for (int j = 0; j < 4; ++j)
            #pragma unroll
            for (int r = 0; r < 4; ++r) {
                int gm = bm + wm + i * 16 + er + r;
                int gn = bn + wn + j * 16 + ec;
                float v = acc[i][j][r];
                if (bias) v += bias[gn];
                if (res) v += res[(size_t)gm * rsC + gn];
                Cf[(size_t)gm * rsC + gn] = v;
            }
}

// ---------------- 128x64 GEMM 32x32 frags; grid (8, 64) -----------------------
__global__ __launch_bounds__(256)
void gemm3_n64(const ushort_t* __restrict__ A2, int rsA,
               const ushort_t* __restrict__ B2, int rsB,
               const float* __restrict__ bias,
               const float* __restrict__ res,
               float* __restrict__ Cf, int rsC, int Kp) {
    __shared__ __align__(16) ushort_t lds[12288];
    const int tid = threadIdx.x;
    const int bn = blockIdx.x * 64, bm = blockIdx.y * 128;
    const int w = tid >> 6, l = tid & 63;
    const int wm = (w & 1) * 64, wn = (w >> 1) * 32;

    f32x16 acc[2];
    #pragma unroll
    for (int i = 0; i < 2; ++i)
        #pragma unroll
        for (int r = 0; r < 16; ++r) acc[i][r] = 0.0f;

    const int r0 = tid >> 2;
    const int k8 = (((tid & 3) - (tid >> 3)) & 3) * 8;
    const ushort_t* gA0 = A2 + (size_t)(bm + r0) * rsA + k8;
    const ushort_t* gA1 = A2 + (size_t)(bm + 64 + r0) * rsA + k8;
    const ushort_t* gB0 = B2 + (size_t)(bn + r0) * rsB + k8;
    ushort_t* l0 = lds + tid * 8;
    ushort_t* l1 = lds + 2048 + tid * 8;

    const int ar = l & 31, qh = l >> 5;

    for (int kt = 0; kt < Kp; kt += 32) {
        gl_lds16(gA0 + kt, l0);
        gl_lds16(gA1 + kt, l1);
        gl_lds16(gA0 + kt + Kp, l0 + 4096);
        gl_lds16(gA1 + kt + Kp, l1 + 4096);
        gl_lds16(gB0 + kt, l0 + 8192);
        gl_lds16(gB0 + kt + Kp, l0 + 10240);
        __syncthreads();

        #pragma unroll
        for (int kh = 0; kh < 2; ++kh) {
            const int kq = kh * 2 + qh;
            bf16x8 ah[2], al_[2];
            #pragma unroll
            for (int i = 0; i < 2; ++i) {
                int row = wm + i * 32 + ar;
                int ba = row * 32 + (((kq + (row >> 1)) & 3) * 8);
                ah[i]  = *(const bf16x8*)&lds[ba];
                al_[i] = *(const bf16x8*)&lds[4096 + ba];
            }
            int rowb = wn + ar;
            int bb = rowb * 32 + (((kq + (rowb >> 1)) & 3) * 8);
            bf16x8 bh = *(const bf16x8*)&lds[8192 + bb];
            bf16x8 bl = *(const bf16x8*)&lds[10240 + bb];
            #pragma unroll
            for (int i = 0; i < 2; ++i) {
                acc[i] = MFMA32(ah[i], bh, acc[i]);
                acc[i] = MFMA32(ah[i], bl, acc[i]);
                acc[i] = MFMA32(al_[i], bh, acc[i]);
            }
        }
        __syncthreads();
    }

    const int ec = l & 31, rb = (l >> 5) * 4;
    int gn = bn + wn + ec;
    float bv = bias ? bias[gn] : 0.0f;
    #pragma unroll
    for (int i = 0; i < 2; ++i)
        #pragma unroll
        for (int r = 0; r < 16; ++r) {
            int gm = bm + wm + i * 32 + rb + (r & 3) + 8 * (r >> 2);
            float v = acc[i][r] + bv;
            if (res) v += res[(size_t)gm * rsC + gn];
            Cf[(size_t)gm * rsC + gn] = v;
        }
}

// ---------------- encoder GEMM (A exact-bf16, hi only); grid (16, 64) ---------
__global__ __launch_bounds__(256)
void gemm3_enc(const ushort_t* __restrict__ A2, const ushort_t* __restrict__ B2,
               const float* __restrict__ bc, ushort_t* __restrict__ cat2) {
    const int bn = blockIdx.x * 64;
    if (bn >= 640) return;
    const int bm = blockIdx.y * 128;
    __shared__ __align__(16) ushort_t lds[8192];
    const int tid = threadIdx.x;
    const int w = tid >> 6, l = tid & 63;
    const int wm = (w & 1) * 64, wn = (w >> 1) * 32;
    const int Kp = 288;

    f32x16 acc[2];
    #pragma unroll
    for (int i = 0; i < 2; ++i)
        #pragma unroll
        for (int r = 0; r < 16; ++r) acc[i][r] = 0.0f;

    const int r0 = tid >> 2;
    const int k8 = (((tid & 3) - (tid >> 3)) & 3) * 8;
    const ushort_t* gA0 = A2 + (size_t)(bm + r0) * 288 + k8;
    const ushort_t* gA1 = A2 + (size_t)(bm + 64 + r0) * 288 + k8;
    const ushort_t* gB0 = B2 + (size_t)(bn + r0) * 576 + k8;
    ushort_t* l0 = lds + tid * 8;
    ushort_t* l1 = lds + 2048 + tid * 8;
    const int ar = l & 31, qh = l >> 5;

    for (int kt = 0; kt < Kp; kt += 32) {
        gl_lds16(gA0 + kt, l0);
        gl_lds16(gA1 + kt, l1);
        gl_lds16(gB0 + kt, l0 + 4096);
        gl_lds16(gB0 + kt + Kp, l0 + 6144);
        __syncthreads();
        #pragma unroll
        for (int kh = 0; kh < 2; ++kh) {
            const int kq = kh * 2 + qh;
            bf16x8 ah[2];
            #pragma unroll
            for (int i = 0; i < 2; ++i) {
                int row = wm + i * 32 + ar;
                int ba = row * 32 + (((kq + (row >> 1)) & 3) * 8);
                ah[i] = *(const bf16x8*)&lds[ba];
            }
            int rowb = wn + ar;
            int bb = rowb * 32 + (((kq + (rowb >> 1)) & 3) * 8);
            bf16x8 bh = *(const bf16x8*)&lds[4096 + bb];
            bf16x8 bl = *(const bf16x8*)&lds[6144 + bb];
            #pragma unroll
            for (int i = 0; i < 2; ++i) {
                acc[i] = MFMA32(ah[i], bh, acc[i]);
                acc[i] = MFMA32(ah[i], bl, acc[i]);
            }
        }
        __syncthreads();
    }

    const int ec = l & 31, rb = (l >> 5) * 4;
    int gn = bn + wn + ec;
    if (gn < 576) {
        float bv = bc[gn];
        #pragma unroll
        for (int i = 0; i < 2; ++i)
            #pragma unroll
            for (int r = 0; r < 16; ++r) {
                int gm = bm + wm + i * 32 + rb + (r & 3) + 8 * (r >> 2);
                float v = silu_f(acc[i][r] + bv);
                ushort_t hi, lo;
                split2(v, hi, lo);
                cat2[(size_t)gm * 1536 + 192 + gn] = hi;
                cat2[(size_t)gm * 1536 + 960 + gn] = lo;
            }
    }
}

// ---------------- fused GLU GEMM (128x128, 16x16 frags); grid (16, 64) --------
__global__ __launch_bounds__(256)
void gemm_glu3(const ushort_t* __restrict__ A2,
               const ushort_t* __restrict__ W1, const ushort_t* __restrict__ W3,
               const float* __restrict__ b1, const float* __restrict__ b3,
               ushort_t* __restrict__ C2) {
    const int bn = blockIdx.x * 128;
    if (bn >= DFFP) return;
    const int bm = blockIdx.y * 128;
    __shared__ __align__(16) ushort_t lds[6 * 4096];
    const int tid = threadIdx.x;
    const int w = tid >> 6, l = tid & 63;
    const int wm = (w & 1) * 64, wn = (w >> 1) * 64;
    const int Kp = 512;

    f32x4 acc1[4][4], acc3[4][4];
    #pragma unroll
    for (int i = 0; i < 4; ++i)
        #pragma unroll
        for (int j = 0; j < 4; ++j) {
            acc1[i][j] = (f32x4){0.f, 0.f, 0.f, 0.f};
            acc3[i][j] = (f32x4){0.f, 0.f, 0.f, 0.f};
        }

    const int r0 = tid >> 2;
    const int k8 = (((tid & 3) - (tid >> 3)) & 3) * 8;
    const ushort_t* gA0 = A2 + (size_t)(bm + r0) * 1024 + k8;
    const ushort_t* gA1 = A2 + (size_t)(bm + 64 + r0) * 1024 + k8;
    const ushort_t* g10 = W1 + (size_t)(bn + r0) * 1024 + k8;
    const ushort_t* g11 = W1 + (size_t)(bn + 64 + r0) * 1024 + k8;
    const ushort_t* g30 = W3 + (size_t)(bn + r0) * 1024 + k8;
    const ushort_t* g31 = W3 + (size_t)(bn + 64 + r0) * 1024 + k8;
    ushort_t* l0 = lds + tid * 8;
    ushort_t* l1 = lds + 2048 + tid * 8;
    const int fr = l & 15, q = l >> 4;

    for (int kt = 0; kt < Kp; kt += 32) {
        gl_lds16(gA0 + kt, l0);
        gl_lds16(gA1 + kt, l1);
        gl_lds16(gA0 + kt + Kp, l0 + 4096);
        gl_lds16(gA1 + kt + Kp, l1 + 4096);
        gl_lds16(g10 + kt, l0 + 8192);
        gl_lds16(g11 + kt, l1 + 8192);
        gl_lds16(g10 + kt + Kp, l0 + 12288);
        gl_lds16(g11 + kt + Kp, l1 + 12288);
        gl_lds16(g30 + kt, l0 + 16384);
        gl_lds16(g31 + kt, l1 + 16384);
        gl_lds16(g30 + kt + Kp, l0 + 20480);
        gl_lds16(g31 + kt + Kp, l1 + 20480);
        __syncthreads();

        bf16x8 ahi[4], alo[4];
        #pragma unroll
        for (int i = 0; i < 4; ++i) {
            int rowa = wm + i * 16 + fr;
            int ba = rowa * 32 + (((q + (rowa >> 1)) & 3) * 8);
            ahi[i] = *(const bf16x8*)&lds[ba];
            alo[i] = *(const bf16x8*)&lds[4096 + ba];
        }
        #pragma unroll
        for (int j = 0; j < 4; ++j) {
            int rowb = wn + j * 16 + fr;
            int bb = rowb * 32 + (((q + (rowb >> 1)) & 3) * 8);
            bf16x8 w1h = *(const bf16x8*)&lds[8192 + bb];
            bf16x8 w1l = *(const bf16x8*)&lds[12288 + bb];
            bf16x8 w3h = *(const bf16x8*)&lds[16384 + bb];
            bf16x8 w3l = *(const bf16x8*)&lds[20480 + bb];
            #pragma unroll
            for (int i = 0; i < 4; ++i) {
                acc1[i][j] = MFMA16(ahi[i], w1h, acc1[i][j]);
                acc1[i][j] = MFMA16(ahi[i], w1l, acc1[i][j]);
                acc1[i][j] = MFMA16(alo[i], w1h, acc1[i][j]);
                acc3[i][j] = MFMA16(ahi[i], w3h, acc3[i][j]);
                acc3[i][j] = MFMA16(ahi[i], w3l, acc3[i][j]);
                acc3[i][j] = MFMA16(alo[i], w3h, acc3[i][j]);
            }
        }
        __syncthreads();
    }

    const int er = (l >> 4) * 4, ec = l & 15;
    #pragma unroll
    for (int i = 0; i < 4; ++i)
        #pragma unroll
        for (int j = 0; j < 4; ++j)
            #pragma unroll
            for (int r = 0; r < 4; ++r) {
                int gm = bm + wm + i * 16 + er + r;
                int gn = bn + wn + j * 16 + ec;
                if (gn < KP2) {
                    float u1 = acc1[i][j][r], u3 = acc3[i][j][r];
                    if (gn < DFF) { u1 += b1[gn]; u3 += b3[gn]; }
                    float g = silu_f(u1) * u3;
                    ushort_t hi, lo;
                    split2(g, hi, lo);
                    C2[(size_t)gm * (2 * KP2) + gn] = hi;
                    C2[(size_t)gm * (2 * KP2) + KP2 + gn] = lo;
                }
            }
}

// ---------------- per-token reductions (wave-per-token) -----------------------
__global__ __launch_bounds__(256)
void rms_kernel(const float* __restrict__ h, const float* __restrict__ w,
                ushort_t* __restrict__ out2) {
    int wid = threadIdx.x >> 6, lane = threadIdx.x & 63;
    int t = blockIdx.x * 4 + wid;
    const float* hp = h + (size_t)t * 512;
    float2 xv[4];
    float ss = 0.0f;
    #pragma unroll
    for (int u = 0; u < 4; ++u) {
        xv[u] = *(const float2*)&hp[u * 128 + lane * 2];
        ss += xv[u].x * xv[u].x + xv[u].y * xv[u].y;
    }
    #pragma unroll
    for (int off = 32; off > 0; off >>= 1) ss += __shfl_xor(ss, off, 64);
    float inv = rsqrtf(ss * (1.0f / 512.0f) + 1.1920929e-07f);
    ushort_t* op = out2 + (size_t)t * 1024;
    #pragma unroll
    for (int u = 0; u < 4; ++u) {
        float2 wv = *(const float2*)&w[u * 128 + lane * 2];
        ushort2 hv, lv;
        split2(xv[u].x * inv * wv.x, hv.x, lv.x);
        split2(xv[u].y * inv * wv.y, hv.y, lv.y);
        *(ushort2*)&op[u * 128 + lane * 2] = hv;
        *(ushort2*)&op[512 + u * 128 + lane * 2] = lv;
    }
}

__global__ __launch_bounds__(256)
void ln_silu_kernel(const float* __restrict__ h, const float* __restrict__ w,
                    const float* __restrict__ b, float* __restrict__ out) {
    int wid = threadIdx.x >> 6, lane = threadIdx.x & 63;
    int t = blockIdx.x * 4 + wid;
    const float* hp = h + (size_t)t * 512;
    float xv[8];
    float s = 0.0f;
    #pragma unroll
    for (int u = 0; u < 8; ++u) { xv[u] = hp[u * 64 + lane]; s += xv[u]; }
    #pragma unroll
    for (int off = 32; off > 0; off >>= 1) s += __shfl_xor(s, off, 64);
    float m = s * (1.0f / 512.0f);
    float v = 0.0f;
    #pragma unroll
    for (int u = 0; u < 8; ++u) { xv[u] -= m; v += xv[u] * xv[u]; }
    #pragma unroll
    for (int off = 32; off > 0; off >>= 1) v += __shfl_xor(v, off, 64);
    float inv = rsqrtf(v * (1.0f / 512.0f) + 1e-5f);
    float* op = out + (size_t)t * 512;
    #pragma unroll
    for (int u = 0; u < 8; ++u)
        op[u * 64 + lane] = silu_f(xv[u] * inv * w[u * 64 + lane] + b[u * 64 + lane]);
}

// ---------------- MFMA local attention (16x16 path) ---------------------------
__global__ __launch_bounds__(256)
void attn_kernel(const float* __restrict__ qkv, const float* __restrict__ ct,
                 const float* __restrict__ st, ushort_t* __restrict__ attn2) {
    __shared__ __align__(16) ushort_t Khi[32 * 64], Klo[32 * 64];
    __shared__ __align__(16) ushort_t Vthi[64 * 32], Vtlo[64 * 32];
    __shared__ __align__(16) ushort_t Phi[128 * 32], Plo[128 * 32];
    const int nb = blockIdx.x, head = blockIdx.y, b = blockIdx.z;
    const int tid = threadIdx.x;
    const int w = tid >> 6, lane = tid & 63;
    const int quad = lane >> 4, lc = lane & 15;

    bf16x8 qhi[2][2], qlo[2][2];
    #pragma unroll
    for (int i = 0; i < 2; ++i) {
        int qtok = nb * 128 + w * 32 + i * 16 + lc;
        const float* qp = qkv + ((size_t)(b * LSEQ + qtok)) * 1536 + head * 64;
        #pragma unroll
        for (int s = 0; s < 2; ++s) {
            float4 a = *(const float4*)&qp[s * 32 + quad * 8];
            float4 bq = *(const float4*)&qp[s * 32 + quad * 8 + 4];
            float4 c4 = *(const float4*)&ct[qtok * 32 + s * 16 + quad * 4];
            float4 s4 = *(const float4*)&st[qtok * 32 + s * 16 + quad * 4];
            float e[8];
            e[0] = (a.x * c4.x - a.y * s4.x) * 0.125f;
            e[1] = (a.x * s4.x + a.y * c4.x) * 0.125f;
            e[2] = (a.z * c4.y - a.w * s4.y) * 0.125f;
            e[3] = (a.z * s4.y + a.w * c4.y) * 0.125f;
            e[4] = (bq.x * c4.z - bq.y * s4.z) * 0.125f;
            e[5] = (bq.x * s4.z + bq.y * c4.z) * 0.125f;
            e[6] = (bq.z * c4.w - bq.w * s4.w) * 0.125f;
            e[7] = (bq.z * s4.w + bq.w * c4.w) * 0.125f;
            union { bf16x8 v; ushort_t u[8]; } hh, ll;
            #pragma unroll
            for (int d = 0; d < 8; ++d) split2(e[d], hh.u[d], ll.u[d]);
            qhi[i][s] = hh.v;
            qlo[i][s] = ll.v;
        }
    }

    f32x4 acc[2][4];
    float mrun[2][4], lrun[2][4];
    #pragma unroll
    for (int i = 0; i < 2; ++i) {
        #pragma unroll
        for (int j = 0; j < 4; ++j) acc[i][j] = (f32x4){0.f, 0.f, 0.f, 0.f};
        #pragma unroll
        for (int r = 0; r < 4; ++r) { mrun[i][r] = -1e30f; lrun[i][r] = 0.0f; }
    }

    const int c0 = (nb == 0) ? 4 : 0;
    for (int c = c0; c < 8; ++c) {
        {
            int key = tid >> 3, g = tid & 7;
            int ktok = nb * 128 - 128 + c * 32 + key;
            const float* kp = qkv + ((size_t)(b * LSEQ + ktok)) * 1536 + 512 + head * 64 + g * 8;
            float4 a = *(const float4*)kp;
            float4 bq = *(const float4*)(kp + 4);
            float4 c4 = *(const float4*)&ct[ktok * 32 + g * 4];
            float4 s4 = *(const float4*)&st[ktok * 32 + g * 4];
            float e[8];
            e[0] = a.x * c4.x - a.y * s4.x;
            e[1] = a.x * s4.x + a.y * c4.x;
            e[2] = a.z * c4.y - a.w * s4.y;
            e[3] = a.z * s4.y + a.w * c4.y;
            e[4] = bq.x * c4.z - bq.y * s4.z;
            e[5] = bq.x * s4.z + bq.y * c4.z;
            e[6] = bq.z * c4.w - bq.w * s4.w;
            e[7] = bq.z * s4.w + bq.w * c4.w;
            union { bf16x8 v; ushort_t u[8]; } hh, ll;
            #pragma unroll
            for (int d = 0; d < 8; ++d) split2(e[d], hh.u[d], ll.u[d]);
            int sg = g ^ (key & 7);
            *(bf16x8*)&Khi[key * 64 + sg * 8] = hh.v;
            *(bf16x8*)&Klo[key * 64 + sg * 8] = ll.v;

            const float* vp = kp + 512;
            float4 va = *(const float4*)vp;
            float4 vb = *(const float4*)(vp + 4);
            float ve[8] = {va.x, va.y, va.z, va.w, vb.x, vb.y, vb.z, vb.w};
            int kg = key >> 3, k7 = key & 7;
            #pragma unroll
            for (int d = 0; d < 8; ++d) {
                ushort_t vh, vl;
                split2(ve[d], vh, vl);
                int dim = g * 8 + d;
                int addr = dim * 32 + (((kg + (dim >> 1)) & 3) * 8) + k7;
                Vthi[addr] = vh;
                Vtlo[addr] = vl;
            }
        }
        __syncthreads();

        f32x4 sf[2][2];
        #pragma unroll
        for (int i = 0; i < 2; ++i)
            #pragma unroll
            for (int t = 0; t < 2; ++t) sf[i][t] = (f32x4){0.f, 0.f, 0.f, 0.f};
        #pragma unroll
        for (int t = 0; t < 2; ++t) {
            #pragma unroll
            for (int s = 0; s < 2; ++s) {
                int row = t * 16 + lc;
                int sg = (s * 4 + quad) ^ (row & 7);
                bf16x8 kh = *(const bf16x8*)&Khi[row * 64 + sg * 8];
                bf16x8 kl = *(const bf16x8*)&Klo[row * 64 + sg * 8];
                #pragma unroll
                for (int i = 0; i < 2; ++i) {
                    sf[i][t] = MFMA16(qhi[i][s], kh, sf[i][t]);
                    sf[i][t] = MFMA16(qhi[i][s], kl, sf[i][t]);
                    sf[i][t] = MFMA16(qlo[i][s], kh, sf[i][t]);
                }
            }
        }

        #pragma unroll
        for (int i = 0; i < 2; ++i) {
            #pragma unroll
            for (int r = 0; r < 4; ++r) {
                int qq = w * 32 + i * 16 + quad * 4 + r;
                float rm = -1e30f;
                #pragma unroll
                for (int t = 0; t < 2; ++t) {
                    int key = c * 32 + t * 16 + lc;
                    bool valid = (key >= qq) && (key <= qq + 128) && (nb > 0 || key >= 128);
                    float sv = valid ? sf[i][t][r] : -1e30f;
                    sf[i][t][r] = sv;
                    rm = fmaxf(rm, sv);
                }
                #pragma unroll
                for (int xm = 1; xm < 16; xm <<= 1)
                    rm = fmaxf(rm, __shfl_xor(rm, xm, 64));
                float mn = fmaxf(mrun[i][r], rm);
                float alpha = __expf(mrun[i][r] - mn);
                lrun[i][r] *= alpha;
                #pragma unroll
                for (int j = 0; j < 4; ++j) acc[i][j][r] *= alpha;
                float rs = 0.0f;
                #pragma unroll
                for (int t = 0; t < 2; ++t) {
                    int key = c * 32 + t * 16 + lc;
                    bool valid = (key >= qq) && (key <= qq + 128) && (nb > 0 || key >= 128);
                    float p = valid ? __expf(sf[i][t][r] - mn) : 0.0f;
                    rs += p;
                    ushort_t ph, pl;
                    split2(p, ph, pl);
                    int col = t * 16 + lc;
                    int addr = qq * 32 + ((((col >> 3) + (qq >> 1)) & 3) * 8) + (col & 7);
                    Phi[addr] = ph;
                    Plo[addr] = pl;
                }
                #pragma unroll
                for (int xm = 1; xm < 16; xm <<= 1)
                    rs += __shfl_xor(rs, xm, 64);
                lrun[i][r] += rs;
                mrun[i][r] = mn;
            }
        }

        bf16x8 ph[2], pl[2];
        #pragma unroll
        for (int i = 0; i < 2; ++i) {
            int row = w * 32 + i * 16 + lc;
            int sg = (quad + (row >> 1)) & 3;
            ph[i] = *(const bf16x8*)&Phi[row * 32 + sg * 8];
            pl[i] = *(const bf16x8*)&Plo[row * 32 + sg * 8];
        }
        #pragma unroll
        for (int j = 0; j < 4; ++j) {
            int dim = j * 16 + lc;
            int sg = (quad + (dim >> 1)) & 3;
            bf16x8 vh = *(const bf16x8*)&Vthi[dim * 32 + sg * 8];
            bf16x8 vl = *(const bf16x8*)&Vtlo[dim * 32 + sg * 8];
            #pragma unroll
            for (int i = 0; i < 2; ++i) {
                acc[i][j] = MFMA16(ph[i], vh, acc[i][j]);
                acc[i][j] = MFMA16(ph[i], vl, acc[i][j]);
                acc[i][j] = MFMA16(pl[i], vh, acc[i][j]);
            }
        }
        __syncthreads();
    }

    #pragma unroll
    for (int i = 0; i < 2; ++i) {
        #pragma unroll
        for (int r = 0; r < 4; ++r) {
            int qtok = nb * 128 + w * 32 + i * 16 + quad * 4 + r;
            size_t base = ((size_t)(b * LSEQ + qtok)) * 1024 + head * 64;
            float inv = 1.0f / lrun[i][r];
            #pragma unroll
            for (int j = 0; j < 4; ++j) {
                float v = acc[i][j][r] * inv;
                ushort_t hi, lo;
                split2(v, hi, lo);
                attn2[base + j * 16 + lc] = hi;
                attn2[base + 512 + j * 16 + lc] = lo;
            }
        }
    }
}

// ---------------- head: LN + silu + 31-dim head + postprocess -----------------
__global__ __launch_bounds__(256)
void head_kernel(const float* __restrict__ h, const float* __restrict__ lw,
                 const float* __restrict__ lb, const float* __restrict__ head_w,
                 const float* __restrict__ head_b, float* __restrict__ out) {
    int wid = threadIdx.x >> 6, lane = threadIdx.x & 63;
    int t = blockIdx.x * 4 + wid;
    __shared__ float yv[4][32];
    const float* xr = h + (size_t)t * 512;
    float xv[8];
    float s = 0.0f;
    #pragma unroll
    for (int u = 0; u < 8; ++u) { xv[u] = xr[u * 64 + lane]; s += xv[u]; }
    #pragma unroll
    for (int off = 32; off > 0; off >>= 1) s += __shfl_xor(s, off, 64);
    float m = s * (1.0f / 512.0f);
    float var = 0.0f;
    #pragma unroll
    for (int u = 0; u < 8; ++u) { xv[u] -= m; var += xv[u] * xv[u]; }
    #pragma unroll
    for (int off = 32; off > 0; off >>= 1) var += __shfl_xor(var, off, 64);
    float inv = rsqrtf(var * (1.0f / 512.0f) + 1e-5f);
    #pragma unroll
    for (int u = 0; u < 8; ++u)
        xv[u] = silu_f(xv[u] * inv * lw[u * 64 + lane] + lb[u * 64 + lane]);

    for (int j = 0; j < 31; ++j) {
        const float* wr = head_w + (size_t)j * 512;
        float p = 0.0f;
        #pragma unroll
        for (int u = 0; u < 8; ++u) p += xv[u] * wr[u * 64 + lane];
        #pragma unroll
        for (int off = 32; off > 0; off >>= 1) p += __shfl_down(p, off, 64);
        if (lane == 0) yv[wid][j] = p + head_b[j];
    }
    if (lane == 0) {
        float* y = yv[wid];
        float* op = out + (size_t)t * 40;
        int am = 0; float best = y[0];
        for (int j = 1; j < 11; ++j) if (y[j] > best) { best = y[j]; am = j; }
        float fc_reg = softplus_f(y[11]);
        op[0] = (am < 10) ? (float)(am + 1) : fc_reg;
        for (int j = 0; j < 11; ++j) op[1 + j] = y[j];
        op[12] = fc_reg;
        int am2 = 0; float best2 = y[12];
        for (int j = 1; j < 11; ++j) if (y[12 + j] > best2) { best2 = y[12 + j]; am2 = j; }
        float ec_reg = softplus_f(y[23]);
        op[13] = (am2 < 10) ? (float)(am2 + 1) : ec_reg;
        for (int j = 0; j < 11; ++j) op[14 + j] = y[12 + j];
        op[25] = ec_reg;
        float bm_log = y[24];
        op[26] = 1.0f / (1.0f + expf(-bm_log));
        float mi = fmaxf(y[25], fmaxf(y[26], y[27]));
        float e0 = expf(y[25] - mi), e1 = expf(y[26] - mi), e2 = expf(y[27] - mi);
        float si = e0 + e1 + e2;
        op[27] = e0 / si; op[28] = e1 / si; op[29] = e2 / si;
        float md = fmaxf(y[28], fmaxf(y[29], y[30]));
        float d0 = expf(y[28] - md), d1 = expf(y[29] - md), d2 = expf(y[30] - md);
        float sd = d0 + d1 + d2;
        op[30] = d0 / sd; op[31] = d1 / sd; op[32] = d2 / sd;
        op[33] = bm_log;
        op[34] = y[25]; op[35] = y[26]; op[36] = y[27];
        op[37] = y[28]; op[38] = y[29]; op[39] = y[30];
    }
}

// ---------------- launch -------------------------------------------------------
extern "C" void kernel_launch(void* const* d_in, const int* in_sizes, int n_in,
                              void* d_out, int out_size, void* d_ws, size_t ws_size,
                              hipStream_t stream) {
    const int*   x        = (const int*)d_in[0];
    const float* emb      = (const float*)d_in[1];
    const float* reg_w    = (const float*)d_in[2];
    const float* reg_b    = (const float*)d_in[3];
    const float* br_w     = (const float*)d_in[4];
    const float* br_b     = (const float*)d_in[5];
    const float* sh_w     = (const float*)d_in[6];
    const float* sh_b     = (const float*)d_in[7];
    const float* inst_w   = (const float*)d_in[8];
    const float* inst_b   = (const float*)d_in[9];
    const float* enc_ln_w = (const float*)d_in[10];
    const float* enc_ln_b = (const float*)d_in[11];
    const float* qkv_w    = (const float*)d_in[12];
    const float* out_w    = (const float*)d_in[13];
    const float* out_b    = (const float*)d_in[14];
    const float* w1_w     = (const float*)d_in[15];
    const float* w1_b     = (const float*)d_in[16];
    const float* w3_w     = (const float*)d_in[17];
    const float* w3_b     = (const float*)d_in[18];
    const float* w2_w     = (const float*)d_in[19];
    const float* w2_b     = (const float*)d_in[20];
    const float* n1_w     = (const float*)d_in[21];
    const float* n2_w     = (const float*)d_in[22];
    const float* hl_w     = (const float*)d_in[23];
    const float* hl_b     = (const float*)d_in[24];
    const float* head_w   = (const float*)d_in[25];
    const float* head_b   = (const float*)d_in[26];

    char* ws = (char*)d_ws;
    size_t off = 0;
    ushort_t* inst2 = (ushort_t*)(ws + off); off += (size_t)512 * 1536 * 2;
    ushort_t* qkv2  = (ushort_t*)(ws + off); off += (size_t)3 * 1536 * 1024 * 2;
    ushort_t* out2w = (ushort_t*)(ws + off); off += (size_t)3 * 512 * 1024 * 2;
    ushort_t* w1s   = (ushort_t*)(ws + off); off += (size_t)3 * DFFP * 1024 * 2;
    ushort_t* w3s   = (ushort_t*)(ws + off); off += (size_t)3 * DFFP * 1024 * 2;
    ushort_t* w2s   = (ushort_t*)(ws + off); off += (size_t)3 * 512 * (2 * KP2) * 2;
    float*    ct    = (float*)(ws + off);    off += (size_t)LSEQ * 32 * 4;
    float*    st    = (float*)(ws + off);    off += (size_t)LSEQ * 32 * 4;
    float*    h     = (float*)(ws + off);    off += (size_t)T_TOK * 512 * 4;
    ushort_t* x2    = (ushort_t*)(ws + off); off += (size_t)T_TOK * 1024 * 2;
    ushort_t* attn2 = (ushort_t*)(ws + off); off += (size_t)T_TOK * 1024 * 2;
    float*    qkvb  = (float*)(ws + off);    off += (size_t)T_TOK * 1536 * 4;
    ushort_t* cat2  = (ushort_t*)(ws + off); off += (size_t)T_TOK * (2 * KP2) * 2;
    ushort_t* Wc2   = (ushort_t*)(ws + off); off += (size_t)640 * 576 * 2;
    float*    bc    = (float*)(ws + off);    off += 640 * 4;
    ushort_t* g2    = cat2;
    ushort_t* X2    = (ushort_t*)qkvb;

    prep_const<<<896, 256, 0, stream>>>(ct, st, reg_w, reg_b, br_w, br_b,
                                        sh_w, sh_b, Wc2, bc);
    prep_tok<<<T_TOK, 256, 0, stream>>>(x, emb, X2, cat2);
    splitw_kernel<<<dim3(3, 512), 256, 0, stream>>>(inst_w, inst2, 512, 768, 768);
    splitw_qkv_kernel<<<dim3(2, 1536, 3), 256, 0, stream>>>(qkv_w, qkv2);
    splitw_kernel<<<dim3(2, 3 * 512), 256, 0, stream>>>(out_w, out2w, 3 * 512, 512, 512);
    splitw_ffn<<<dim3(2, 3 * DFFP), 256, 0, stream>>>(w1_w, w3_w, w1s, w3s);
    splitw_w2<<<dim3(6, 3 * 512), 256, 0, stream>>>(w2_w, w2s);

    gemm3_enc<<<dim3(16, 64), 256, 0, stream>>>(X2, Wc2, bc, cat2);
    gemm3_n64<<<dim3(8, 64), 256, 0, stream>>>(
        cat2, 1536, inst2, 1536, inst_b, nullptr, h, 512, 768);
    ln_silu_kernel<<<T_TOK / 4, 256, 0, stream>>>(h, enc_ln_w, enc_ln_b, h);

    for (int l = 0; l < NLAYER; ++l) {
        rms_kernel<<<T_TOK / 4, 256, 0, stream>>>(h, n1_w + l * 512, x2);
        gemm3_kernel<<<dim3(16, 64), 256, 0, stream>>>(
            x2, 1024, qkv2 + (size_t)l * 1536 * 1024, 1024, nullptr, nullptr,
            qkvb, 1536, 512, 1536);
        {
            dim3 g(NBLK, NHEAD, BATCH);
            attn_kernel<<<g, 256, 0, stream>>>(qkvb, ct, st, attn2);
        }
        gemm3_n64<<<dim3(8, 64), 256, 0, stream>>>(
            attn2, 1024, out2w + (size_t)l * 512 * 1024, 1024, out_b + l * 512,
            h, h, 512, 512);
        rms_kernel<<<T_TOK / 4, 256, 0, stream>>>(h, n2_w + l * 512, x2);
        gemm_glu3<<<dim3(16, 64), 256, 0, stream>>>(
            x2, w1s + (size_t)l * DFFP * 1024, w3s + (size_t)l * DFFP * 1024,
            w1_b + l * DFF, w3_b + l * DFF, g2);
        gemm3_n64<<<dim3(8, 64), 256, 0, stream>>>(
            g2, 2 * KP2, w2s + (size_t)l * 512 * (2 * KP2), 2 * KP2, w2_b + l * 512,
            h, h, 512, KP2);
    }

    head_kernel<<<T_TOK / 4, 256, 0, stream>>>(h, hl_w, hl_b, head_w, head_b,
                                               (float*)d_out);
}